// Round 5
// baseline (162.546 us; speedup 1.0000x reference)
//
#include <hip/hip_runtime.h>
#include <hip/hip_bf16.h>
#include <cstdint>

typedef __attribute__((ext_vector_type(8))) short short8;
typedef __attribute__((ext_vector_type(16))) float f32x16;

#if __has_builtin(__builtin_amdgcn_exp2f)
#define EXP2F(x) __builtin_amdgcn_exp2f(x)
#else
#define EXP2F(x) exp2f(x)
#endif

#define MFMA32(A, B, C) __builtin_amdgcn_mfma_f32_32x32x16_bf16((A), (B), (C), 0, 0, 0)

// fp32 -> bf16, round-to-nearest-even
__device__ __forceinline__ unsigned short f2bf(float f) {
  unsigned int u = __builtin_bit_cast(unsigned int, f);
  u += 0x7FFFu + ((u >> 16) & 1u);
  return (unsigned short)(u >> 16);
}

// ---------------------------------------------------------------------------
// Prep: Wt[which][n][k] = f2bf(W_which[k][n]),  3 x 64 x 512 bf16.
// ---------------------------------------------------------------------------
__global__ __launch_bounds__(256) void prep_wt(
    const float* __restrict__ Wq, const float* __restrict__ Wk,
    const float* __restrict__ Wv, unsigned short* __restrict__ Wt)
{
  int idx = blockIdx.x * 256 + threadIdx.x;     // 384 blocks
  int which = idx >> 15;
  int rem = idx & 32767;
  int n = rem >> 9;
  int k = rem & 511;
  const float* W = (which == 0) ? Wq : (which == 1) ? Wk : Wv;
  Wt[idx] = f2bf(W[k * 64 + n]);
}

// ---------------------------------------------------------------------------
// Fused projection, LDS-staged GEMM with double-buffered staging (R5):
//   grid (256, 3): by = which (0:Q scaled, 1:K, 2:V -> Vt[b][64][2048]).
//   block = 256 = 4 waves: grp = wv&1 (rows), nh = wv>>1 (cols).
//   Tile M=64, N=64, BK=128, 4 chunks, 2 LDS buffers (34.8 KB): chunk c+1's
//   global loads issue before chunk c's MFMAs; ONE barrier per chunk.
//   Xs row stride 136 elems = 272B: 16B-aligned, write/read bank-balanced.
//   768 blocks = 3/CU.
// ---------------------------------------------------------------------------
__global__ __launch_bounds__(256, 3) void proj_kernel(
    const float* __restrict__ qin, const float* __restrict__ kin,
    const float* __restrict__ vin, const unsigned short* __restrict__ Wt,
    const float* __restrict__ bq, const float* __restrict__ bk,
    const float* __restrict__ bv,
    unsigned short* __restrict__ Qo, unsigned short* __restrict__ Ko,
    unsigned short* __restrict__ Vto)
{
  __shared__ unsigned short Xs[2][64 * 136];   // 34.8 KB; Xs[0] reused as TB for V

  const int which = blockIdx.y;
  const float* X    = (which == 0) ? qin : (which == 1) ? kin : vin;
  const float* bias = (which == 0) ? bq  : (which == 1) ? bk  : bv;

  const int tid = threadIdx.x;
  const int lane = tid & 63, wv = tid >> 6;
  const int h = lane >> 5, l31 = lane & 31;
  const int grp = wv & 1, nh = wv >> 1;
  const int m0 = blockIdx.x * 64;

  // W B-frag base: n = nh*32 + l31 on lanes, k = h*8 + j (L2-resident)
  const unsigned short* wcol =
      Wt + (size_t)which * 64 * 512 + (size_t)(nh * 32 + l31) * 512 + h * 8;

  // staging coords: thread covers rows srow+8j, 16B k-offset skoff
  const int srow = tid >> 5;        // 0..7
  const int skoff = tid & 31;       // 16B units within 512B chunk-row
  const float* xg = X + (size_t)(m0 + srow) * 512 + skoff * 4;

  // prologue: stage chunk 0 into Xs[0]
  #pragma unroll
  for (int j = 0; j < 8; ++j) {
    float4 a = *(const float4*)(xg + (size_t)(8 * j) * 512);
    unsigned int w0 = (unsigned int)f2bf(a.x) | ((unsigned int)f2bf(a.y) << 16);
    unsigned int w1 = (unsigned int)f2bf(a.z) | ((unsigned int)f2bf(a.w) << 16);
    uint2 pw; pw.x = w0; pw.y = w1;
    *(uint2*)(&Xs[0][(srow + 8 * j) * 136 + skoff * 4]) = pw;
  }
  __syncthreads();

  f32x16 acc = {};
  for (int c = 0; c < 4; ++c) {
    // prefetch chunk c+1 into regs (issues before the MFMA dependence chain)
    float4 pf[8];
    if (c < 3) {
      #pragma unroll
      for (int j = 0; j < 8; ++j)
        pf[j] = *(const float4*)(xg + (size_t)(8 * j) * 512 + (c + 1) * 128);
    }
    // compute chunk c from Xs[c&1]
    const unsigned short* arow = &Xs[c & 1][(grp * 32 + l31) * 136 + h * 8];
    const unsigned short* wk = wcol + c * 128;
    #pragma unroll
    for (int ks = 0; ks < 8; ++ks) {
      short8 af = *(const short8*)(arow + ks * 16);
      short8 bf = *(const short8*)(wk + ks * 16);
      acc = MFMA32(af, bf, acc);
    }
    // publish chunk c+1 into the alternate buffer
    if (c < 3) {
      unsigned short* dst = Xs[(c + 1) & 1];
      #pragma unroll
      for (int j = 0; j < 8; ++j) {
        unsigned int w0 = (unsigned int)f2bf(pf[j].x) | ((unsigned int)f2bf(pf[j].y) << 16);
        unsigned int w1 = (unsigned int)f2bf(pf[j].z) | ((unsigned int)f2bf(pf[j].w) << 16);
        uint2 pw; pw.x = w0; pw.y = w1;
        *(uint2*)(&dst[(srow + 8 * j) * 136 + skoff * 4]) = pw;
      }
      __syncthreads();
    }
  }

  const float bv0 = bias[nh * 32 + l31];

  if (which < 2) {
    const float scale = which ? 1.0f : 0.18033688f;  // (1/sqrt(64))*log2(e) for Q
    unsigned short* Y = which ? Ko : Qo;
    #pragma unroll
    for (int r = 0; r < 16; ++r) {
      int row = (r & 3) + 8 * (r >> 2) + 4 * h;      // C/D layout [m101]
      Y[(size_t)(m0 + grp * 32 + row) * 64 + nh * 32 + l31] =
          f2bf((acc[r] + bv0) * scale);
    }
  } else {
    __syncthreads();                // all waves done with main loop
    unsigned short* TB = Xs[0];     // [64 n][68 s]
    #pragma unroll
    for (int r = 0; r < 16; ++r) {
      int row = (r & 3) + 8 * (r >> 2) + 4 * h;
      TB[(nh * 32 + l31) * 68 + grp * 32 + row] = f2bf(acc[r] + bv0);
    }
    __syncthreads();
    int bidx = blockIdx.x >> 5;        // 32 blocks per batch (64 rows each)
    int s0 = (blockIdx.x & 31) * 64;
    for (int i = tid; i < 64 * 16; i += 256) {   // 64 n x 16 ushort4 chunks
      int n = i >> 4, cs = i & 15;
      ushort4 v4 = *(const ushort4*)(TB + n * 68 + cs * 4);
      *(ushort4*)(Vto + ((size_t)bidx * 64 + n) * 2048 + s0 + cs * 4) = v4;
    }
  }
}

// ---------------------------------------------------------------------------
// Flash attention, transposed formulation. R5 change: 1D grid with
// batch = bx & 7 so all 32 blocks of a batch land on one XCD (round-robin
// dispatch heuristic) -> that XCD's L2 working set is 512 KB (its batch's
// K+V) instead of 4 MB (all batches) -> K/V re-reads become L2 hits.
// ---------------------------------------------------------------------------
__global__ __launch_bounds__(512, 2) void attn_kernel(
    const unsigned short* __restrict__ Q, const unsigned short* __restrict__ K,
    const unsigned short* __restrict__ Vt, float* __restrict__ out)
{
  __shared__ float ObS[4][16][64];
  __shared__ float MpS[4][64];
  __shared__ float LpS[4][64];

  const int tid = threadIdx.x;
  const int lane = tid & 63, w = tid >> 6;
  const int h = lane >> 5, l31 = lane & 31;
  const int b = blockIdx.x & 7;            // batch -> XCD (L2 locality)
  const int q0 = (blockIdx.x >> 3) * 64;   // q-tile

  short8 qf[2][4];
  #pragma unroll
  for (int qt = 0; qt < 2; ++qt) {
    const unsigned short* qp = Q + ((size_t)(b * 2048 + q0 + qt * 32 + l31)) * 64 + h * 8;
    #pragma unroll
    for (int c = 0; c < 4; ++c) qf[qt][c] = *(const short8*)(qp + c * 16);
  }

  f32x16 o00 = {}, o01 = {}, o10 = {}, o11 = {};
  float m0 = -1e30f, m1 = -1e30f, ls0 = 0.f, ls1 = 0.f;

  for (int st = 0; st < 8; ++st) {
    const int kb = w * 256 + st * 32;
    short8 kf[4];
    const unsigned short* kp = K + ((size_t)(b * 2048 + kb + l31)) * 64 + h * 8;
    #pragma unroll
    for (int c = 0; c < 4; ++c) kf[c] = *(const short8*)(kp + c * 16);
    short8 vf0[2], vf1[2];
    {
      const unsigned short* vp0 = Vt + ((size_t)(b * 64 + l31)) * 2048 + kb + h * 8;
      const unsigned short* vp1 = Vt + ((size_t)(b * 64 + 32 + l31)) * 2048 + kb + h * 8;
      vf0[0] = *(const short8*)(vp0);  vf0[1] = *(const short8*)(vp0 + 16);
      vf1[0] = *(const short8*)(vp1);  vf1[1] = *(const short8*)(vp1 + 16);
    }
    #pragma unroll
    for (int qt = 0; qt < 2; ++qt) {
      f32x16 sT = {};
      #pragma unroll
      for (int c = 0; c < 4; ++c) sT = MFMA32(kf[c], qf[qt][c], sT);
      float mx = sT[0];
      #pragma unroll
      for (int r = 1; r < 16; ++r) mx = fmaxf(mx, sT[r]);
      mx = fmaxf(mx, __shfl_xor(mx, 32, 64));
      float mold = qt ? m1 : m0;
      float mnew = fmaxf(mold, mx);
      float alpha = EXP2F(mold - mnew);
      float rs = 0.f;
      float p[16];
      #pragma unroll
      for (int r = 0; r < 16; ++r) { p[r] = EXP2F(sT[r] - mnew); rs += p[r]; }
      rs += __shfl_xor(rs, 32, 64);
      unsigned int pk[8];
      #pragma unroll
      for (int i = 0; i < 8; ++i)
        pk[i] = (unsigned int)f2bf(p[2 * i]) | ((unsigned int)f2bf(p[2 * i + 1]) << 16);
      unsigned int ex[8];
      #pragma unroll
      for (int i = 0; i < 8; ++i) ex[i] = (unsigned int)__shfl_xor((int)pk[i], 32, 64);
      uint4 cc0, cc1;
      if (h == 0) { cc0 = make_uint4(pk[0], pk[1], ex[0], ex[1]); cc1 = make_uint4(pk[4], pk[5], ex[4], ex[5]); }
      else        { cc0 = make_uint4(ex[2], ex[3], pk[2], pk[3]); cc1 = make_uint4(ex[6], ex[7], pk[6], pk[7]); }
      short8 P0 = __builtin_bit_cast(short8, cc0);
      short8 P1 = __builtin_bit_cast(short8, cc1);
      if (qt == 0) {
        m0 = mnew; ls0 = ls0 * alpha + rs;
        o00 *= alpha; o10 *= alpha;
        o00 = MFMA32(vf0[0], P0, o00); o00 = MFMA32(vf0[1], P1, o00);
        o10 = MFMA32(vf1[0], P0, o10); o10 = MFMA32(vf1[1], P1, o10);
      } else {
        m1 = mnew; ls1 = ls1 * alpha + rs;
        o01 *= alpha; o11 *= alpha;
        o01 = MFMA32(vf0[0], P0, o01); o01 = MFMA32(vf0[1], P1, o01);
        o11 = MFMA32(vf1[0], P0, o11); o11 = MFMA32(vf1[1], P1, o11);
      }
    }
  }

  for (int half = 4; half > 0; half >>= 1) {
    const bool writer = (w >= half) && (w < 2 * half);
    const bool merger = (w < half);
    __syncthreads();
    if (writer && h == 0) {
      MpS[w - half][l31] = m0;      LpS[w - half][l31] = ls0;
      MpS[w - half][32 + l31] = m1; LpS[w - half][32 + l31] = ls1;
    }
    __syncthreads();
    float fb0 = 0.f, fb1 = 0.f;
    if (merger) {
      float pm0 = MpS[w][l31],      pl0 = LpS[w][l31];
      float pm1 = MpS[w][32 + l31], pl1 = LpS[w][32 + l31];
      float nm0 = fmaxf(m0, pm0), nm1 = fmaxf(m1, pm1);
      float fa0 = EXP2F(m0 - nm0); fb0 = EXP2F(pm0 - nm0);
      float fa1 = EXP2F(m1 - nm1); fb1 = EXP2F(pm1 - nm1);
      m0 = nm0; m1 = nm1;
      ls0 = ls0 * fa0 + pl0 * fb0; ls1 = ls1 * fa1 + pl1 * fb1;
      o00 *= fa0; o10 *= fa0; o01 *= fa1; o11 *= fa1;
    }
    __syncthreads();
    if (writer) {
      #pragma unroll
      for (int r = 0; r < 16; ++r) ObS[w - half][r][lane] = o00[r]; }
    __syncthreads();
    if (merger) {
      #pragma unroll
      for (int r = 0; r < 16; ++r) o00[r] += ObS[w][r][lane] * fb0; }
    __syncthreads();
    if (writer) {
      #pragma unroll
      for (int r = 0; r < 16; ++r) ObS[w - half][r][lane] = o01[r]; }
    __syncthreads();
    if (merger) {
      #pragma unroll
      for (int r = 0; r < 16; ++r) o01[r] += ObS[w][r][lane] * fb1; }
    __syncthreads();
    if (writer) {
      #pragma unroll
      for (int r = 0; r < 16; ++r) ObS[w - half][r][lane] = o10[r]; }
    __syncthreads();
    if (merger) {
      #pragma unroll
      for (int r = 0; r < 16; ++r) o10[r] += ObS[w][r][lane] * fb0; }
    __syncthreads();
    if (writer) {
      #pragma unroll
      for (int r = 0; r < 16; ++r) ObS[w - half][r][lane] = o11[r]; }
    __syncthreads();
    if (merger) {
      #pragma unroll
      for (int r = 0; r < 16; ++r) o11[r] += ObS[w][r][lane] * fb1; }
  }

  if (w == 0) {
    float i0 = 1.0f / ls0, i1 = 1.0f / ls1;
    o00 *= i0; o10 *= i0; o01 *= i1; o11 *= i1;
    #pragma unroll
    for (int qt = 0; qt < 2; ++qt) {
      int q = qt * 32 + l31;
      float* ob = out + ((size_t)(b * 2048 + q0 + q)) * 64 + 4 * h;
      const f32x16 a = qt ? o01 : o00;
      const f32x16 c = qt ? o11 : o10;
      #pragma unroll
      for (int g = 0; g < 4; ++g) {
        *(float4*)(ob + 8 * g)      = make_float4(a[4*g], a[4*g+1], a[4*g+2], a[4*g+3]);
        *(float4*)(ob + 32 + 8 * g) = make_float4(c[4*g], c[4*g+1], c[4*g+2], c[4*g+3]);
      }
    }
  }
}

extern "C" void kernel_launch(void* const* d_in, const int* in_sizes, int n_in,
                              void* d_out, int out_size, void* d_ws, size_t ws_size,
                              hipStream_t stream) {
  const float* qin = (const float*)d_in[0];
  const float* kin = (const float*)d_in[1];
  const float* vin = (const float*)d_in[2];
  const float* Wq  = (const float*)d_in[3];
  const float* bq  = (const float*)d_in[4];
  const float* Wk  = (const float*)d_in[5];
  const float* bk  = (const float*)d_in[6];
  const float* Wv  = (const float*)d_in[7];
  const float* bv  = (const float*)d_in[8];

  unsigned short* Qo  = (unsigned short*)d_ws;            // [8*2048][64] bf16 (pre-scaled)
  unsigned short* Ko  = Qo + (size_t)16384 * 64;          // [8*2048][64] bf16
  unsigned short* Vto = Ko + (size_t)16384 * 64;          // [8][64][2048] bf16 (transposed)
  unsigned short* Wt  = Vto + (size_t)8 * 64 * 2048;      // [3][64][512] bf16 W^T
  float* out = (float*)d_out;

  hipLaunchKernelGGL(prep_wt, dim3(384), dim3(256), 0, stream, Wq, Wk, Wv, Wt);
  hipLaunchKernelGGL(proj_kernel, dim3(256, 3), dim3(256), 0, stream,
                     qin, kin, vin, Wt, bq, bk, bv, Qo, Ko, Vto);
  hipLaunchKernelGGL(attn_kernel, dim3(256), dim3(512), 0, stream, Qo, Ko, Vto, out);
}